// Round 3
// baseline (580.100 us; speedup 1.0000x reference)
//
#include <hip/hip_runtime.h>
#include <math.h>

// Two-phase LSTM. B=1024,T=256,D=128,H=64,G=256,O=128.
// Phase 1 (gx_gemm, 1024 blocks): gx = x.Wih^T + (bih+bhh), bf16, stored
//   PRE-PERMUTED as gxp[t][blk][tid][16] = exactly the MFMA C-layout the
//   scan consumes (coalesced 32B/thread loads, no per-step x work).
// Phase 2 (lstm_rec, 64 blocks x 16 batches): per step only the recurrence:
//   acc init from gxp, 8 MFMA (h.Whh^T, 2-chain), activations in-reg,
//   one barrier/step. c-state in registers for all 256 steps.
constexpr int B = 1024, T = 256, D = 128, H = 64, G = 256, O = 128;
constexpr int BQ = 16;
constexpr int XPAD = 8, HPAD = 8;
constexpr int NBLK = B / BQ;                       // 64 scan blocks
constexpr size_t TSTRIDE = (size_t)NBLK * 256 * 16; // gxp elems per t

typedef __attribute__((ext_vector_type(8))) short short8;
typedef __attribute__((ext_vector_type(4))) float f32x4;

__device__ __forceinline__ unsigned short f2bf(float f) {
    union { float f; unsigned u; } v; v.f = f;
    return (unsigned short)((v.u + 0x7FFF + ((v.u >> 16) & 1)) >> 16);  // RNE
}
__device__ __forceinline__ float frcp(float x) { return __builtin_amdgcn_rcpf(x); }
__device__ __forceinline__ float bf_lo(unsigned v) {
    union { unsigned u; float f; } x; x.u = v << 16; return x.f;
}
__device__ __forceinline__ float bf_hi(unsigned v) {
    union { unsigned u; float f; } x; x.u = v & 0xffff0000u; return x.f;
}
__device__ __forceinline__ float sigmoidf_(float x) {
    return frcp(1.0f + __expf(-x));
}
__device__ __forceinline__ float tanhf_(float x) {
    float a = fabsf(x);
    float e = __expf(2.0f * a);                 // inf -> r=1 (overflow-safe)
    float r = fmaf(-2.0f, frcp(e + 1.0f), 1.0f);
    return copysignf(r, x);
}

// ---------------- Phase 1: input projection, permuted bf16 ----------------
__global__ __launch_bounds__(256, 1)
void gx_gemm(const float* __restrict__ x, const float* __restrict__ Wih,
             const float* __restrict__ bih, const float* __restrict__ bhh,
             unsigned short* __restrict__ gxp)
{
    const int tid = threadIdx.x;
    const int lane = tid & 63, w = tid >> 6;
    const int lq = lane & 15, qd = lane >> 4;
    const int blkB = blockIdx.x, t0 = blockIdx.y * 16;
    const int b0 = blkB * BQ;

    short8 wih_f[4][4];
    float bias[4];
    #pragma unroll
    for (int q = 0; q < 4; ++q) {
        const int n = 64 * q + 16 * w + lq;
        #pragma unroll
        for (int c = 0; c < 4; ++c) {
            const float* p = Wih + (size_t)n * D + 32 * c + 8 * qd;
            short8 v;
            #pragma unroll
            for (int j = 0; j < 8; ++j) v[j] = (short)f2bf(p[j]);
            wih_f[q][c] = v;
        }
        bias[q] = bih[n] + bhh[n];
    }

    for (int tt = 0; tt < 16; ++tt) {
        const int t = t0 + tt;
        // A-frag: lane = x[b0+lq][t][32c+8qd .. +7]
        short8 xf[4];
        #pragma unroll
        for (int c = 0; c < 4; ++c) {
            const float* p = x + ((size_t)(b0 + lq) * T + t) * D + 32 * c + 8 * qd;
            float4 a = *(const float4*)p, b2 = *(const float4*)(p + 4);
            short8 v;
            v[0] = (short)f2bf(a.x);  v[1] = (short)f2bf(a.y);
            v[2] = (short)f2bf(a.z);  v[3] = (short)f2bf(a.w);
            v[4] = (short)f2bf(b2.x); v[5] = (short)f2bf(b2.y);
            v[6] = (short)f2bf(b2.z); v[7] = (short)f2bf(b2.w);
            xf[c] = v;
        }
        f32x4 acc[4];
        #pragma unroll
        for (int q = 0; q < 4; ++q) {
            f32x4 a = {bias[q], bias[q], bias[q], bias[q]};
            #pragma unroll
            for (int c = 0; c < 4; ++c)
                a = __builtin_amdgcn_mfma_f32_16x16x32_bf16(xf[c], wih_f[q][c], a, 0, 0, 0);
            acc[q] = a;
        }
        // pack 16 bf16, one contiguous 32B store per thread
        short8 o0, o1;
        #pragma unroll
        for (int i = 0; i < 4; ++i) {
            o0[i]     = (short)f2bf(acc[0][i]);
            o0[i + 4] = (short)f2bf(acc[1][i]);
            o1[i]     = (short)f2bf(acc[2][i]);
            o1[i + 4] = (short)f2bf(acc[3][i]);
        }
        unsigned short* dst = gxp + (size_t)t * TSTRIDE + ((size_t)blkB * 256 + tid) * 16;
        *(short8*)dst = o0;
        *(short8*)(dst + 8) = o1;
    }
}

// ---------------- Phase 2: recurrence-only scan ----------------
__global__ __launch_bounds__(256, 1)
void lstm_rec(const unsigned short* __restrict__ gxp,
              const float* __restrict__ Whh, const float* __restrict__ Wo,
              const float* __restrict__ bo, float* __restrict__ out)
{
    __shared__ unsigned short hs[2][BQ][H + HPAD];
    __shared__ float hf[BQ][H];

    const int tid = threadIdx.x;
    const int lane = tid & 63, w = tid >> 6;
    const int lq = lane & 15, qd = lane >> 4;
    const int b0 = blockIdx.x * BQ;

    short8 whh_f[4][2];
    #pragma unroll
    for (int q = 0; q < 4; ++q) {
        const int n = 64 * q + 16 * w + lq;
        #pragma unroll
        for (int c = 0; c < 2; ++c) {
            const float* p = Whh + (size_t)n * H + 32 * c + 8 * qd;
            short8 v;
            #pragma unroll
            for (int j = 0; j < 8; ++j) v[j] = (short)f2bf(p[j]);
            whh_f[q][c] = v;
        }
    }

    for (int i = tid; i < 2 * BQ * (H + HPAD); i += 256)
        ((unsigned short*)hs)[i] = 0;

    // gx prefetch pipeline, depth 2 (32 B/thread/step, coalesced)
    const unsigned short* gp = gxp + ((size_t)blockIdx.x * 256 + tid) * 16;
    uint4 pf[2][2];
    pf[0][0] = *(const uint4*)gp;
    pf[0][1] = *(const uint4*)(gp + 8);
    pf[1][0] = *(const uint4*)(gp + TSTRIDE);
    pf[1][1] = *(const uint4*)(gp + TSTRIDE + 8);
    __syncthreads();

    float cst[4] = {0.f, 0.f, 0.f, 0.f};
    float hlast[4];
    int cur = 0;

    for (int t = 0; t < T; ++t) {
        const int nxt = cur ^ 1;
        const int s = t & 1;

        // acc init = gx(t) (bias already baked in)
        uint4 ga = pf[s][0], gb = pf[s][1];
        f32x4 acc[4];
        acc[0] = f32x4{bf_lo(ga.x), bf_hi(ga.x), bf_lo(ga.y), bf_hi(ga.y)};
        acc[1] = f32x4{bf_lo(ga.z), bf_hi(ga.z), bf_lo(ga.w), bf_hi(ga.w)};
        acc[2] = f32x4{bf_lo(gb.x), bf_hi(gb.x), bf_lo(gb.y), bf_hi(gb.y)};
        acc[3] = f32x4{bf_lo(gb.z), bf_hi(gb.z), bf_lo(gb.w), bf_hi(gb.w)};

        // reissue prefetch for t+2
        if (t + 2 < T) {
            const unsigned short* p = gp + (size_t)(t + 2) * TSTRIDE;
            pf[s][0] = *(const uint4*)p;
            pf[s][1] = *(const uint4*)(p + 8);
        }

        // h A-frags + 8 MFMA (2-chain per gate)
        short8 hfr[2];
        #pragma unroll
        for (int c = 0; c < 2; ++c)
            hfr[c] = *(const short8*)&hs[cur][lq][32 * c + 8 * qd];
        #pragma unroll
        for (int q = 0; q < 4; ++q) {
            #pragma unroll
            for (int c = 0; c < 2; ++c)
                acc[q] = __builtin_amdgcn_mfma_f32_16x16x32_bf16(hfr[c], whh_f[q][c], acc[q], 0, 0, 0);
        }

        // activations + state update (cell (m=4qd+r, j=16w+lq) in this lane)
        const int j = 16 * w + lq;
        #pragma unroll
        for (int r = 0; r < 4; ++r) {
            float gi = sigmoidf_(acc[0][r]);
            float gf = sigmoidf_(acc[1][r]);
            float gg = tanhf_  (acc[2][r]);
            float go = sigmoidf_(acc[3][r]);
            float c2 = gf * cst[r] + gi * gg;
            cst[r] = c2;
            float hv = go * tanhf_(c2);
            hlast[r] = hv;
            hs[nxt][4 * qd + r][j] = f2bf(hv);
        }

        __syncthreads();
        cur = nxt;
    }

    // epilogue: logits = relu(h) Wo^T + bo ; log_softmax over O=128
    #pragma unroll
    for (int r = 0; r < 4; ++r) hf[4 * qd + r][16 * w + lq] = hlast[r];
    __syncthreads();

    for (int it = 0; it < 4; ++it) {
        const int m = 4 * it + w;
        float l0 = bo[lane], l1 = bo[lane + 64];
        const float* w0 = Wo + (size_t)lane * H;
        const float* w1 = Wo + (size_t)(lane + 64) * H;
        #pragma unroll
        for (int k = 0; k < H; ++k) {
            float rh = fmaxf(hf[m][k], 0.0f);
            l0 += rh * w0[k];
            l1 += rh * w1[k];
        }
        float mx = fmaxf(l0, l1);
        #pragma unroll
        for (int sh = 32; sh > 0; sh >>= 1) mx = fmaxf(mx, __shfl_xor(mx, sh));
        float e = __expf(l0 - mx) + __expf(l1 - mx);
        #pragma unroll
        for (int sh = 32; sh > 0; sh >>= 1) e += __shfl_xor(e, sh);
        float lse = mx + __logf(e);
        float* op = out + (size_t)(b0 + m) * O;
        op[lane]      = l0 - lse;
        op[lane + 64] = l1 - lse;
    }
}

// ---------------- Fallback (round-2 fused kernel, used if ws too small) ----
__global__ __launch_bounds__(256, 1)
void lstm_mfma(const float* __restrict__ x, const float* __restrict__ Wih,
               const float* __restrict__ Whh, const float* __restrict__ bih,
               const float* __restrict__ bhh, const float* __restrict__ Wo,
               const float* __restrict__ bo, float* __restrict__ out)
{
    __shared__ unsigned short xs[2][BQ][D + XPAD];
    __shared__ unsigned short hs[2][BQ][H + HPAD];
    __shared__ float hf[BQ][H];

    const int tid = threadIdx.x;
    const int lane = tid & 63, w = tid >> 6;
    const int lq = lane & 15, qd = lane >> 4;
    const int b0 = blockIdx.x * BQ;

    short8 wih_f[4][4]; short8 whh_f[4][2]; float bias[4];
    #pragma unroll
    for (int q = 0; q < 4; ++q) {
        const int n = 64 * q + 16 * w + lq;
        #pragma unroll
        for (int c = 0; c < 4; ++c) {
            const float* p = Wih + (size_t)n * D + 32 * c + 8 * qd;
            short8 v;
            #pragma unroll
            for (int j = 0; j < 8; ++j) v[j] = (short)f2bf(p[j]);
            wih_f[q][c] = v;
        }
        #pragma unroll
        for (int c = 0; c < 2; ++c) {
            const float* p = Whh + (size_t)n * H + 32 * c + 8 * qd;
            short8 v;
            #pragma unroll
            for (int j = 0; j < 8; ++j) v[j] = (short)f2bf(p[j]);
            whh_f[q][c] = v;
        }
        bias[q] = bih[n] + bhh[n];
    }

    const int ms = tid >> 4, ks = (tid & 15) * 8;
    {
        const float* p = x + ((size_t)(b0 + ms) * T + 0) * D + ks;
        float4 a = *(const float4*)p, bv = *(const float4*)(p + 4);
        short8 v;
        v[0] = (short)f2bf(a.x);  v[1] = (short)f2bf(a.y);
        v[2] = (short)f2bf(a.z);  v[3] = (short)f2bf(a.w);
        v[4] = (short)f2bf(bv.x); v[5] = (short)f2bf(bv.y);
        v[6] = (short)f2bf(bv.z); v[7] = (short)f2bf(bv.w);
        *(short8*)&xs[0][ms][ks] = v;
    }
    for (int i = tid; i < 2 * BQ * (H + HPAD); i += 256)
        ((unsigned short*)hs)[i] = 0;
    float4 pa, pb;
    {
        const float* p = x + ((size_t)(b0 + ms) * T + 1) * D + ks;
        pa = *(const float4*)p; pb = *(const float4*)(p + 4);
    }
    __syncthreads();

    float cst[4] = {0.f, 0.f, 0.f, 0.f};
    float hlast[4];
    int cur = 0;
    for (int t = 0; t < T; ++t) {
        const int nxt = cur ^ 1;
        {
            short8 v;
            v[0] = (short)f2bf(pa.x); v[1] = (short)f2bf(pa.y);
            v[2] = (short)f2bf(pa.z); v[3] = (short)f2bf(pa.w);
            v[4] = (short)f2bf(pb.x); v[5] = (short)f2bf(pb.y);
            v[6] = (short)f2bf(pb.z); v[7] = (short)f2bf(pb.w);
            *(short8*)&xs[nxt][ms][ks] = v;
        }
        {
            const int t2 = (t + 2 < T) ? t + 2 : T - 1;
            const float* p = x + ((size_t)(b0 + ms) * T + t2) * D + ks;
            pa = *(const float4*)p; pb = *(const float4*)(p + 4);
        }
        short8 xf[4], hfr[2];
        #pragma unroll
        for (int c = 0; c < 4; ++c)
            xf[c] = *(const short8*)&xs[cur][lq][32 * c + 8 * qd];
        #pragma unroll
        for (int c = 0; c < 2; ++c)
            hfr[c] = *(const short8*)&hs[cur][lq][32 * c + 8 * qd];
        f32x4 acc[4];
        #pragma unroll
        for (int q = 0; q < 4; ++q) {
            f32x4 a = {bias[q], bias[q], bias[q], bias[q]};
            #pragma unroll
            for (int c = 0; c < 4; ++c)
                a = __builtin_amdgcn_mfma_f32_16x16x32_bf16(xf[c], wih_f[q][c], a, 0, 0, 0);
            #pragma unroll
            for (int c = 0; c < 2; ++c)
                a = __builtin_amdgcn_mfma_f32_16x16x32_bf16(hfr[c], whh_f[q][c], a, 0, 0, 0);
            acc[q] = a;
        }
        const int j = 16 * w + lq;
        #pragma unroll
        for (int r = 0; r < 4; ++r) {
            float gi = sigmoidf_(acc[0][r]);
            float gf = sigmoidf_(acc[1][r]);
            float gg = tanhf_  (acc[2][r]);
            float go = sigmoidf_(acc[3][r]);
            float c2 = gf * cst[r] + gi * gg;
            cst[r] = c2;
            float hv = go * tanhf_(c2);
            hlast[r] = hv;
            hs[nxt][4 * qd + r][j] = f2bf(hv);
        }
        __syncthreads();
        cur = nxt;
    }
    #pragma unroll
    for (int r = 0; r < 4; ++r) hf[4 * qd + r][16 * w + lq] = hlast[r];
    __syncthreads();
    for (int it = 0; it < 4; ++it) {
        const int m = 4 * it + w;
        float l0 = bo[lane], l1 = bo[lane + 64];
        const float* w0 = Wo + (size_t)lane * H;
        const float* w1 = Wo + (size_t)(lane + 64) * H;
        #pragma unroll
        for (int k = 0; k < H; ++k) {
            float rh = fmaxf(hf[m][k], 0.0f);
            l0 += rh * w0[k];
            l1 += rh * w1[k];
        }
        float mx = fmaxf(l0, l1);
        #pragma unroll
        for (int sh = 32; sh > 0; sh >>= 1) mx = fmaxf(mx, __shfl_xor(mx, sh));
        float e = __expf(l0 - mx) + __expf(l1 - mx);
        #pragma unroll
        for (int sh = 32; sh > 0; sh >>= 1) e += __shfl_xor(e, sh);
        float lse = mx + __logf(e);
        float* op = out + (size_t)(b0 + m) * O;
        op[lane]      = l0 - lse;
        op[lane + 64] = l1 - lse;
    }
}

extern "C" void kernel_launch(void* const* d_in, const int* in_sizes, int n_in,
                              void* d_out, int out_size, void* d_ws, size_t ws_size,
                              hipStream_t stream) {
    const float* x   = (const float*)d_in[0];
    const float* Wih = (const float*)d_in[1];
    const float* Whh = (const float*)d_in[2];
    const float* bih = (const float*)d_in[3];
    const float* bhh = (const float*)d_in[4];
    const float* Wo  = (const float*)d_in[5];
    const float* bo  = (const float*)d_in[6];
    const size_t need = (size_t)T * NBLK * 256 * 16 * sizeof(unsigned short); // 134.2 MB
    if (ws_size >= need) {
        gx_gemm<<<dim3(NBLK, 16), dim3(256), 0, stream>>>(
            x, Wih, bih, bhh, (unsigned short*)d_ws);
        lstm_rec<<<dim3(NBLK), dim3(256), 0, stream>>>(
            (const unsigned short*)d_ws, Whh, Wo, bo, (float*)d_out);
    } else {
        lstm_mfma<<<dim3(NBLK), dim3(256), 0, stream>>>(
            x, Wih, Whh, bih, bhh, Wo, bo, (float*)d_out);
    }
}

// Round 4
// 443.873 us; speedup vs baseline: 1.3069x; 1.3069x over previous
//
#include <hip/hip_runtime.h>
#include <math.h>

// Fused LSTM, bf16 MFMA, barrier-without-vmcnt-drain.
// B=1024,T=256,D=128,H=64,G=256,O=128. 64 blocks x 256 thr (4 waves);
// block owns 16 batches for the whole scan. Wave w owns gate cols
// {64q+16w+lq}: i,f,g,o for a cell land in one lane -> activations + c-state
// in registers. Weights live as B-fragments in VGPRs.
// KEY (round-4): __syncthreads() would emit s_waitcnt vmcnt(0) before
// s_barrier, draining the x prefetch every step (~900 cyc stall, the round-2/3
// bottleneck). The scan instead uses an LDS-only barrier (lgkmcnt(0)+s_barrier)
// so global prefetch loads stay in flight across steps.
constexpr int B = 1024, T = 256, D = 128, H = 64, O = 128;
constexpr int BQ = 16;
constexpr int XPAD = 8, HPAD = 8;   // bf16 row pad
constexpr int NBLK = B / BQ;        // 64 blocks

typedef __attribute__((ext_vector_type(8))) short short8;
typedef __attribute__((ext_vector_type(4))) float f32x4;

__device__ __forceinline__ unsigned short f2bf(float f) {
    union { float f; unsigned u; } v; v.f = f;
    return (unsigned short)((v.u + 0x7FFF + ((v.u >> 16) & 1)) >> 16);  // RNE
}
__device__ __forceinline__ float frcp(float x) { return __builtin_amdgcn_rcpf(x); }
__device__ __forceinline__ float sigmoidf_(float x) {
    return frcp(1.0f + __expf(-x));                  // exp+rcp quarter-rate
}
__device__ __forceinline__ float tanhf_(float x) {
    // 2/(1+e^-2x)-1: overflow-safe both ways (e=inf -> -1, e=0 -> +1)
    return fmaf(2.0f, frcp(1.0f + __expf(-2.0f * x)), -1.0f);
}
// LDS-visibility barrier that does NOT drain outstanding global loads.
__device__ __forceinline__ void lds_barrier() {
    asm volatile("s_waitcnt lgkmcnt(0)\n\ts_barrier" ::: "memory");
}

__global__ __launch_bounds__(256, 1)
void lstm_fused(const float* __restrict__ x, const float* __restrict__ Wih,
                const float* __restrict__ Whh, const float* __restrict__ bih,
                const float* __restrict__ bhh, const float* __restrict__ Wo,
                const float* __restrict__ bo, float* __restrict__ out)
{
    __shared__ unsigned short xs[2][BQ][D + XPAD];  // x_t bf16, dbuf
    __shared__ unsigned short hs[2][BQ][H + HPAD];  // h_t bf16, dbuf
    __shared__ float hf[BQ][H];                     // final h fp32

    const int tid  = threadIdx.x;
    const int lane = tid & 63;
    const int w    = tid >> 6;     // wave 0..3 -> j-slice [16w,16w+16)
    const int lq   = lane & 15;
    const int qd   = lane >> 4;    // 0..3
    const int b0   = blockIdx.x * BQ;

    // ---- weight B-fragments (constant over t) ----
    short8 wih_f[4][4];            // [gate q][k-chunk c]
    short8 whh_f[4][2];
    float  bias[4];
    #pragma unroll
    for (int q = 0; q < 4; ++q) {
        const int n = 64 * q + 16 * w + lq;
        #pragma unroll
        for (int c = 0; c < 4; ++c) {
            const float* p = Wih + (size_t)n * D + 32 * c + 8 * qd;
            short8 v;
            #pragma unroll
            for (int j = 0; j < 8; ++j) v[j] = (short)f2bf(p[j]);
            wih_f[q][c] = v;
        }
        #pragma unroll
        for (int c = 0; c < 2; ++c) {
            const float* p = Whh + (size_t)n * H + 32 * c + 8 * qd;
            short8 v;
            #pragma unroll
            for (int j = 0; j < 8; ++j) v[j] = (short)f2bf(p[j]);
            whh_f[q][c] = v;
        }
        bias[q] = bih[n] + bhh[n];
    }

    // ---- stage x(0); zero h; prime 2-deep x prefetch (x(1), x(2)) ----
    const int ms = tid >> 4;          // batch row this thread stages
    const int ks = (tid & 15) * 8;    // 8-float chunk (coalesced per row)
    {
        const float* p = x + ((size_t)(b0 + ms) * T + 0) * D + ks;
        float4 a = *(const float4*)p, bv = *(const float4*)(p + 4);
        short8 v;
        v[0] = (short)f2bf(a.x);  v[1] = (short)f2bf(a.y);
        v[2] = (short)f2bf(a.z);  v[3] = (short)f2bf(a.w);
        v[4] = (short)f2bf(bv.x); v[5] = (short)f2bf(bv.y);
        v[6] = (short)f2bf(bv.z); v[7] = (short)f2bf(bv.w);
        *(short8*)&xs[0][ms][ks] = v;
    }
    for (int i = tid; i < 2 * BQ * (H + HPAD); i += 256)
        ((unsigned short*)hs)[i] = 0;

    float4 pfa[2], pfb[2];   // ping-pong prefetch: slot t&1 holds x(t+1)
    #pragma unroll
    for (int s = 0; s < 2; ++s) {
        const float* p = x + ((size_t)(b0 + ms) * T + (1 + s)) * D + ks;
        pfa[s] = *(const float4*)p;
        pfb[s] = *(const float4*)(p + 4);
    }
    __syncthreads();   // once, before the scan: full barrier is fine here

    float cst[4] = {0.f, 0.f, 0.f, 0.f};  // c for (m=4qd+r, j=16w+lq)
    float hlast[4];
    int cur = 0;

    for (int t = 0; t < T; ++t) {
        const int nxt = cur ^ 1;
        const int s = t & 1;

        // A-fragments for this step
        short8 xf[4], hfr[2];
        #pragma unroll
        for (int c = 0; c < 4; ++c)
            xf[c] = *(const short8*)&xs[cur][lq][32 * c + 8 * qd];
        #pragma unroll
        for (int c = 0; c < 2; ++c)
            hfr[c] = *(const short8*)&hs[cur][lq][32 * c + 8 * qd];

        // commit x(t+1) (loaded 2 steps ago -> latency long since covered)
        {
            float4 a = pfa[s], bv = pfb[s];
            short8 v;
            v[0] = (short)f2bf(a.x);  v[1] = (short)f2bf(a.y);
            v[2] = (short)f2bf(a.z);  v[3] = (short)f2bf(a.w);
            v[4] = (short)f2bf(bv.x); v[5] = (short)f2bf(bv.y);
            v[6] = (short)f2bf(bv.z); v[7] = (short)f2bf(bv.w);
            *(short8*)&xs[nxt][ms][ks] = v;
        }
        // reissue prefetch for x(t+3); stays in flight across the barrier
        {
            const int t3 = (t + 3 < T) ? t + 3 : T - 1;
            const float* p = x + ((size_t)(b0 + ms) * T + t3) * D + ks;
            pfa[s] = *(const float4*)p;
            pfb[s] = *(const float4*)(p + 4);
        }

        // gates: acc[q][r] = gate q for cell (m=4qd+r, j=16w+lq)
        f32x4 acc[4];
        #pragma unroll
        for (int q = 0; q < 4; ++q) {
            f32x4 a = {bias[q], bias[q], bias[q], bias[q]};
            #pragma unroll
            for (int c = 0; c < 4; ++c)
                a = __builtin_amdgcn_mfma_f32_16x16x32_bf16(xf[c], wih_f[q][c], a, 0, 0, 0);
            #pragma unroll
            for (int c = 0; c < 2; ++c)
                a = __builtin_amdgcn_mfma_f32_16x16x32_bf16(hfr[c], whh_f[q][c], a, 0, 0, 0);
            acc[q] = a;
        }

        // activations + state update, all in registers
        const int j = 16 * w + lq;
        #pragma unroll
        for (int r = 0; r < 4; ++r) {
            float gi = sigmoidf_(acc[0][r]);
            float gf = sigmoidf_(acc[1][r]);
            float gg = tanhf_  (acc[2][r]);
            float go = sigmoidf_(acc[3][r]);
            float c2 = fmaf(gf, cst[r], gi * gg);
            cst[r] = c2;
            float hv = go * tanhf_(c2);
            hlast[r] = hv;
            hs[nxt][4 * qd + r][j] = f2bf(hv);
        }

        lds_barrier();   // LDS-only: global prefetch NOT drained
        cur = nxt;
    }

    // ---- epilogue: logits = relu(h) Wo^T + bo ; log_softmax over O=128 ----
    #pragma unroll
    for (int r = 0; r < 4; ++r) hf[4 * qd + r][16 * w + lq] = hlast[r];
    __syncthreads();

    for (int it = 0; it < 4; ++it) {
        const int m = 4 * it + w;
        float l0 = bo[lane], l1 = bo[lane + 64];
        const float* w0 = Wo + (size_t)lane * H;
        const float* w1 = Wo + (size_t)(lane + 64) * H;
        #pragma unroll
        for (int k = 0; k < H; ++k) {
            float rh = fmaxf(hf[m][k], 0.0f);
            l0 += rh * w0[k];
            l1 += rh * w1[k];
        }
        float mx = fmaxf(l0, l1);
        #pragma unroll
        for (int sh = 32; sh > 0; sh >>= 1) mx = fmaxf(mx, __shfl_xor(mx, sh));
        float e = __expf(l0 - mx) + __expf(l1 - mx);
        #pragma unroll
        for (int sh = 32; sh > 0; sh >>= 1) e += __shfl_xor(e, sh);
        float lse = mx + __logf(e);
        float* op = out + (size_t)(b0 + m) * O;
        op[lane]      = l0 - lse;
        op[lane + 64] = l1 - lse;
    }
}

extern "C" void kernel_launch(void* const* d_in, const int* in_sizes, int n_in,
                              void* d_out, int out_size, void* d_ws, size_t ws_size,
                              hipStream_t stream) {
    const float* x   = (const float*)d_in[0];
    const float* Wih = (const float*)d_in[1];
    const float* Whh = (const float*)d_in[2];
    const float* bih = (const float*)d_in[3];
    const float* bhh = (const float*)d_in[4];
    const float* Wo  = (const float*)d_in[5];
    const float* bo  = (const float*)d_in[6];
    lstm_fused<<<dim3(NBLK), dim3(256), 0, stream>>>(
        x, Wih, Whh, bih, bhh, Wo, bo, (float*)d_out);
}

// Round 5
// 351.148 us; speedup vs baseline: 1.6520x; 1.2641x over previous
//
#include <hip/hip_runtime.h>
#include <math.h>

// Fused LSTM, bf16 MFMA, chunked x-staging (round 5).
// B=1024,T=256,D=128,H=64,G=256,O=128. 64 blocks x 256 thr; block owns 16
// batches for the whole scan. Wave w owns gate cols {64q+16w+lq}; i,f,g,o for
// a cell land in one lane; c-state in registers.
// KEY: rounds 2-4 showed per-step time (~2900 cyc) invariant to MFMA count /
// barrier type -> suspected per-step global-load vmcnt stall. This round the
// step loop is LDS-only: x is staged in 8-step chunks (one vmcnt wait per
// chunk, loads issued a full chunk ahead), pre-gathered into MFMA A-frag
// layout (conflict-free ds_read_b128). h also in frag layout.
constexpr int B = 1024, T = 256, D = 128, H = 64, O = 128;
constexpr int BQ = 16;
constexpr int NBLK = B / BQ;   // 64 blocks
constexpr int TC = 8;          // timesteps per chunk
constexpr int NCH = T / TC;    // 32 chunks

typedef __attribute__((ext_vector_type(8))) short short8;
typedef __attribute__((ext_vector_type(4))) float f32x4;

__device__ __forceinline__ unsigned short f2bf(float f) {
    union { float f; unsigned u; } v; v.f = f;
    return (unsigned short)((v.u + 0x7FFF + ((v.u >> 16) & 1)) >> 16);  // RNE
}
__device__ __forceinline__ float frcp(float x) { return __builtin_amdgcn_rcpf(x); }
__device__ __forceinline__ float sigmoidf_(float x) {
    return frcp(1.0f + __expf(-x));
}
__device__ __forceinline__ float tanhf_(float x) {
    return fmaf(2.0f, frcp(1.0f + __expf(-2.0f * x)), -1.0f);  // overflow-safe
}
__device__ __forceinline__ void lds_barrier() {
    asm volatile("s_waitcnt lgkmcnt(0)\n\ts_barrier" ::: "memory");
}

__global__ __launch_bounds__(256, 1)
void lstm_fused(const float* __restrict__ x, const float* __restrict__ Wih,
                const float* __restrict__ Whh, const float* __restrict__ bih,
                const float* __restrict__ bhh, const float* __restrict__ Wo,
                const float* __restrict__ bo, float* __restrict__ out)
{
    // x A-frags: per (buf,tt): 4 chunks x 64 lanes x 8 bf16 = 4 KB slab.
    // byte offset within slab: c*1024 + ((lane*16) ^ (c*32))  [XOR swizzle:
    // reads contiguous/conflict-free, staging writes <=4-way]
    __shared__ unsigned short xfrag[2][TC][4 * 64 * 8];   // 64 KB
    __shared__ unsigned short hfrag[2][2 * 64 * 8];       // 4 KB (c,lane,8)
    __shared__ float hf[BQ][H];                           // 4 KB

    const int tid  = threadIdx.x;
    const int lane = tid & 63;
    const int w    = tid >> 6;
    const int lq   = lane & 15;
    const int qd   = lane >> 4;
    const int b0   = blockIdx.x * BQ;

    // ---- weight B-fragments (constant over t) ----
    short8 wih_f[4][4];
    short8 whh_f[4][2];
    float  bias[4];
    #pragma unroll
    for (int q = 0; q < 4; ++q) {
        const int n = 64 * q + 16 * w + lq;
        #pragma unroll
        for (int c = 0; c < 4; ++c) {
            const float* p = Wih + (size_t)n * D + 32 * c + 8 * qd;
            short8 v;
            #pragma unroll
            for (int j = 0; j < 8; ++j) v[j] = (short)f2bf(p[j]);
            wih_f[q][c] = v;
        }
        #pragma unroll
        for (int c = 0; c < 2; ++c) {
            const float* p = Whh + (size_t)n * H + 32 * c + 8 * qd;
            short8 v;
            #pragma unroll
            for (int j = 0; j < 8; ++j) v[j] = (short)f2bf(p[j]);
            whh_f[q][c] = v;
        }
        bias[q] = bih[n] + bhh[n];
    }

    // ---- staging geometry: thread stages x[b0+ms][t][8*kslot .. +8) ----
    const int ms    = tid >> 4;         // batch row (coalesced: lanes 0..15
    const int kslot = tid & 15;         //  cover 128 contiguous B of one row)
    const int c_p   = kslot >> 2;       // destination A-frag chunk
    const int q_p   = kslot & 3;        // destination qd
    const int l_p   = (q_p << 4) | ms;  // destination frag-lane
    const int xoff  = c_p * 1024 + ((l_p * 16) ^ (c_p * 32));  // bytes in slab
    const float* xrow = x + (size_t)(b0 + ms) * T * D + 8 * kslot;

    // frag-read byte offsets for this lane
    int xro[4], hro[2];
    #pragma unroll
    for (int c = 0; c < 4; ++c) xro[c] = c * 1024 + ((lane * 16) ^ (c * 32));
    #pragma unroll
    for (int c = 0; c < 2; ++c) hro[c] = c * 1024 + lane * 16;

    // h producer scatter target (per r added later): row*8 + (lq&7)
    const int hrow_base = (w >> 1) * 512 +
                          (16 * ((2 * w + (lq >> 3)) & 3) + 4 * qd) * 8 + (lq & 7);

    // ---- zero hfrag; load+commit chunk 0; issue chunk 1 ----
    *(short8*)&hfrag[0][tid * 8 * 2 / 2 - tid * 8 + tid * 8] = short8{0,0,0,0,0,0,0,0}; // lane slot
    // (simpler: each thread zeroes 8 shorts in buf0 and buf1)
    *(short8*)&hfrag[0][tid * 4] = short8{0,0,0,0,0,0,0,0};
    *(short8*)&hfrag[1][tid * 4] = short8{0,0,0,0,0,0,0,0};

    float4 pf[16];   // in-flight chunk loads: 2 float4 per tt
    #pragma unroll
    for (int tt = 0; tt < TC; ++tt) {
        const float* p = xrow + (size_t)tt * D;
        pf[2 * tt]     = *(const float4*)p;
        pf[2 * tt + 1] = *(const float4*)(p + 4);
    }
    #pragma unroll
    for (int tt = 0; tt < TC; ++tt) {
        float4 a = pf[2 * tt], bv = pf[2 * tt + 1];
        short8 v;
        v[0] = (short)f2bf(a.x);  v[1] = (short)f2bf(a.y);
        v[2] = (short)f2bf(a.z);  v[3] = (short)f2bf(a.w);
        v[4] = (short)f2bf(bv.x); v[5] = (short)f2bf(bv.y);
        v[6] = (short)f2bf(bv.z); v[7] = (short)f2bf(bv.w);
        *(short8*)((char*)&xfrag[0][tt][0] + xoff) = v;
    }
    #pragma unroll
    for (int tt = 0; tt < TC; ++tt) {   // issue chunk 1 (consumed next boundary)
        const float* p = xrow + (size_t)(TC + tt) * D;
        pf[2 * tt]     = *(const float4*)p;
        pf[2 * tt + 1] = *(const float4*)(p + 4);
    }
    __syncthreads();

    float cst[4] = {0.f, 0.f, 0.f, 0.f};
    float hlast[4];
    int buf = 0;

    for (int ch = 0; ch < NCH; ++ch) {
        #pragma unroll
        for (int tt = 0; tt < TC; ++tt) {
            const int hcur = tt & 1, hnxt = hcur ^ 1;

            short8 xf[4], hfr[2];
            #pragma unroll
            for (int c = 0; c < 4; ++c)
                xf[c] = *(const short8*)((char*)&xfrag[buf][tt][0] + xro[c]);
            #pragma unroll
            for (int c = 0; c < 2; ++c)
                hfr[c] = *(const short8*)((char*)&hfrag[hcur][0] + hro[c]);

            f32x4 acc[4];
            #pragma unroll
            for (int q = 0; q < 4; ++q) {
                f32x4 a = {bias[q], bias[q], bias[q], bias[q]};
                #pragma unroll
                for (int c = 0; c < 4; ++c)
                    a = __builtin_amdgcn_mfma_f32_16x16x32_bf16(xf[c], wih_f[q][c], a, 0, 0, 0);
                #pragma unroll
                for (int c = 0; c < 2; ++c)
                    a = __builtin_amdgcn_mfma_f32_16x16x32_bf16(hfr[c], whh_f[q][c], a, 0, 0, 0);
                acc[q] = a;
            }

            #pragma unroll
            for (int r = 0; r < 4; ++r) {
                float gi = sigmoidf_(acc[0][r]);
                float gf = sigmoidf_(acc[1][r]);
                float gg = tanhf_  (acc[2][r]);
                float go = sigmoidf_(acc[3][r]);
                float c2 = fmaf(gf, cst[r], gi * gg);
                cst[r] = c2;
                float hv = go * tanhf_(c2);
                hlast[r] = hv;
                hfrag[hnxt][hrow_base + r * 8] = f2bf(hv);
            }

            lds_barrier();
        }

        // ---- chunk boundary: commit chunk ch+1, issue chunk ch+2 ----
        if (ch + 1 < NCH) {
            const int nb = buf ^ 1;
            #pragma unroll
            for (int tt = 0; tt < TC; ++tt) {
                float4 a = pf[2 * tt], bv = pf[2 * tt + 1];  // vmcnt wait here
                short8 v;                                     // (8 steps old)
                v[0] = (short)f2bf(a.x);  v[1] = (short)f2bf(a.y);
                v[2] = (short)f2bf(a.z);  v[3] = (short)f2bf(a.w);
                v[4] = (short)f2bf(bv.x); v[5] = (short)f2bf(bv.y);
                v[6] = (short)f2bf(bv.z); v[7] = (short)f2bf(bv.w);
                *(short8*)((char*)&xfrag[nb][tt][0] + xoff) = v;
            }
            const int ch2 = (ch + 2 < NCH) ? ch + 2 : NCH - 1;
            #pragma unroll
            for (int tt = 0; tt < TC; ++tt) {
                const float* p = xrow + ((size_t)ch2 * TC + tt) * D;
                pf[2 * tt]     = *(const float4*)p;
                pf[2 * tt + 1] = *(const float4*)(p + 4);
            }
            lds_barrier();
            buf = nb;
        }
    }

    // ---- epilogue: logits = relu(h) Wo^T + bo ; log_softmax over O=128 ----
    #pragma unroll
    for (int r = 0; r < 4; ++r) hf[4 * qd + r][16 * w + lq] = hlast[r];
    __syncthreads();

    for (int it = 0; it < 4; ++it) {
        const int m = 4 * it + w;
        float l0 = bo[lane], l1 = bo[lane + 64];
        const float* w0 = Wo + (size_t)lane * H;
        const float* w1 = Wo + (size_t)(lane + 64) * H;
        #pragma unroll
        for (int k = 0; k < H; ++k) {
            float rh = fmaxf(hf[m][k], 0.0f);
            l0 += rh * w0[k];
            l1 += rh * w1[k];
        }
        float mx = fmaxf(l0, l1);
        #pragma unroll
        for (int sh = 32; sh > 0; sh >>= 1) mx = fmaxf(mx, __shfl_xor(mx, sh));
        float e = __expf(l0 - mx) + __expf(l1 - mx);
        #pragma unroll
        for (int sh = 32; sh > 0; sh >>= 1) e += __shfl_xor(e, sh);
        float lse = mx + __logf(e);
        float* op = out + (size_t)(b0 + m) * O;
        op[lane]      = l0 - lse;
        op[lane + 64] = l1 - lse;
    }
}

extern "C" void kernel_launch(void* const* d_in, const int* in_sizes, int n_in,
                              void* d_out, int out_size, void* d_ws, size_t ws_size,
                              hipStream_t stream) {
    const float* x   = (const float*)d_in[0];
    const float* Wih = (const float*)d_in[1];
    const float* Whh = (const float*)d_in[2];
    const float* bih = (const float*)d_in[3];
    const float* bhh = (const float*)d_in[4];
    const float* Wo  = (const float*)d_in[5];
    const float* bo  = (const float*)d_in[6];
    lstm_fused<<<dim3(NBLK), dim3(256), 0, stream>>>(
        x, Wih, Whh, bih, bhh, Wo, bo, (float*)d_out);
}